// Round 1
// baseline (773.864 us; speedup 1.0000x reference)
//
#include <hip/hip_runtime.h>
#include <math.h>

#define TEPS 1e-10f

// ws[0] = global min of radii midpoints (as uint bits), ws[1] = global max.
__global__ void pi_init_mm(unsigned* mm){
    mm[0] = 0x7F800000u; // +inf
    mm[1] = 0u;          // 0 (all radii positive)
}

// radii sorted ascending along K=64 -> per-row min midpoint = 0.5*(r0+r1),
// max midpoint = 0.5*(r62+r63). Positive floats: uint bit order == value order.
__global__ __launch_bounds__(256) void pi_minmax(const float* __restrict__ radii,
                                                 unsigned* __restrict__ mm, long nrows){
    long i = (long)blockIdx.x * blockDim.x + threadIdx.x;
    float lmin = __int_as_float(0x7F800000);
    float lmax = 0.f;
    if (i < nrows){
        const float* rr = radii + i * 64;
        float2 a = *reinterpret_cast<const float2*>(rr);      // r0, r1
        float2 b = *reinterpret_cast<const float2*>(rr + 62); // r62, r63
        lmin = 0.5f * (a.x + a.y);
        lmax = 0.5f * (b.x + b.y);
    }
    #pragma unroll
    for (int m = 32; m >= 1; m >>= 1){
        lmin = fminf(lmin, __shfl_xor(lmin, m));
        lmax = fmaxf(lmax, __shfl_xor(lmax, m));
    }
    if ((threadIdx.x & 63) == 0){
        atomicMin(mm + 0, __float_as_uint(lmin));
        atomicMax(mm + 1, __float_as_uint(lmax));
    }
}

// One wave per ray. Lane k owns sample k.
// Output layout (flat, return order): color[nrows*16] | radial[nrows] | weights[nrows*63] | T_end[nrows]
__global__ __launch_bounds__(256) void pi_integrate(const float* __restrict__ colors,
        const float* __restrict__ dens, const float* __restrict__ radii,
        const unsigned* __restrict__ mm, float* __restrict__ out, long nrows){
    const int lane = threadIdx.x & 63;
    const long row = (long)blockIdx.x * 4 + (threadIdx.x >> 6);
    if (row >= nrows) return;

    const long o_rad  = nrows * 16;
    const long o_w    = nrows * 17;
    const long o_tend = nrows * 80;

    // Issue the 4 KB of color loads early (lane-contiguous float4 -> fully coalesced).
    // float4 index j*64+lane -> element j*256+4*lane -> k = j*16 + lane/4, c_base = 4*(lane&3).
    const float4* cp = reinterpret_cast<const float4*>(colors + row * 1024) + lane;
    float4 cv0 = cp[0];
    float4 cv1 = cp[64];
    float4 cv2 = cp[128];
    float4 cv3 = cp[192];

    float r = radii[row * 64 + lane];
    float d = dens [row * 64 + lane];
    float rn = __shfl_down(r, 1);
    float dn = __shfl_down(d, 1);
    float delta = rn - r;
    float dm = fmaxf(0.5f * (d + dn), 0.f);
    float alpha = (lane < 63) ? (1.f - expf(-delta * dm)) : 0.f;  // lane63: w=0 sentinel
    float s = 1.f - alpha + TEPS;

    // Inclusive prefix product of s over lanes; T[k] = exclusive product (T[0]=1).
    float P = s;
    #pragma unroll
    for (int off = 1; off < 64; off <<= 1){
        float t = __shfl_up(P, off);
        if (lane >= off) P *= t;
    }
    float T = __shfl_up(P, 1);
    if (lane == 0) T = 1.f;
    float w = alpha * T;            // weights[k], lane 63 -> 0
    float tend = __shfl(T, 62);     // T_end = prod_{j<62}(1-a_j+eps)

    if (lane < 63) out[o_w + row * 63 + lane] = w;

    // Fold the midpoint: sum_i w_i*(x_i + x_{i+1}) = sum_k (w_k + w_{k-1}) * x_k
    float wprev = __shfl_up(w, 1);
    if (lane == 0) wprev = 0.f;
    float coef = w + wprev;

    float ws = w;
    float nr = coef * r;            // radial numerator (x2; 0.5 factor applied later)
    #pragma unroll
    for (int m = 32; m >= 1; m >>= 1){
        ws += __shfl_xor(ws, m);
        nr += __shfl_xor(nr, m);
    }

    // Color dot: lane needs coef[k] for k = j*16 + lane/4.
    int kg = lane >> 2;
    float c0 = __shfl(coef, kg);
    float c1 = __shfl(coef, 16 + kg);
    float c2 = __shfl(coef, 32 + kg);
    float c3 = __shfl(coef, 48 + kg);
    float ax = c0*cv0.x + c1*cv1.x + c2*cv2.x + c3*cv3.x;
    float ay = c0*cv0.y + c1*cv1.y + c2*cv2.y + c3*cv3.y;
    float az = c0*cv0.z + c1*cv1.z + c2*cv2.z + c3*cv3.z;
    float aw = c0*cv0.w + c1*cv1.w + c2*cv2.w + c3*cv3.w;
    // Reduce over the 16 lanes sharing the same channel group (bits 2..5).
    #pragma unroll
    for (int m = 4; m < 64; m <<= 1){
        ax += __shfl_xor(ax, m);
        ay += __shfl_xor(ay, m);
        az += __shfl_xor(az, m);
        aw += __shfl_xor(aw, m);
    }
    if (lane < 4){
        float4 o;
        o.x = ax - 1.f; o.y = ay - 1.f; o.z = az - 1.f; o.w = aw - 1.f;
        *reinterpret_cast<float4*>(out + row * 16 + lane * 4) = o;
    }
    if (lane == 0){
        float gmin = __uint_as_float(mm[0]);
        float gmax = __uint_as_float(mm[1]);
        float val = (0.5f * nr) / ws;
        if (val != val) val = __int_as_float(0x7F800000);  // NaN -> +inf (ref: nan_to_num(nan=inf))
        val = fminf(fmaxf(val, gmin), gmax);               // inf -> gmax, matching ref clip
        out[o_rad + row] = val;
        out[o_tend + row] = tend;
    }
}

extern "C" void kernel_launch(void* const* d_in, const int* in_sizes, int n_in,
                              void* d_out, int out_size, void* d_ws, size_t ws_size,
                              hipStream_t stream) {
    const float* colors = (const float*)d_in[0];
    const float* dens   = (const float*)d_in[1];
    const float* radii  = (const float*)d_in[2];
    float* out = (float*)d_out;
    unsigned* mm = (unsigned*)d_ws;
    long nrows = (long)in_sizes[1] / 64;  // densities: (N,R,K,1)

    hipLaunchKernelGGL(pi_init_mm, dim3(1), dim3(1), 0, stream, mm);
    int mb = (int)((nrows + 255) / 256);
    hipLaunchKernelGGL(pi_minmax, dim3(mb), dim3(256), 0, stream, radii, mm, nrows);
    int ib = (int)((nrows + 3) / 4);  // 4 waves (rays) per 256-thread block
    hipLaunchKernelGGL(pi_integrate, dim3(ib), dim3(256), 0, stream, colors, dens, radii, mm, out, nrows);
}